// Round 1
// baseline (953.959 us; speedup 1.0000x reference)
//
#include <hip/hip_runtime.h>

// ---------------- CSR build ----------------

__global__ void k_count(const int* __restrict__ dst, int* __restrict__ deg, int E) {
    int i = blockIdx.x * blockDim.x + threadIdx.x;
    if (i < E) atomicAdd(&deg[dst[i]], 1);
}

// phase A: per-block sums of 2048-element chunks
__global__ void k_scan_a(const int* __restrict__ deg, int* __restrict__ bsum, int n) {
    __shared__ int sdata[256];
    int base = blockIdx.x * 2048;
    int tid = threadIdx.x;
    int sum = 0;
    #pragma unroll
    for (int j = 0; j < 8; j++) {
        int idx = base + tid * 8 + j;
        if (idx < n) sum += deg[idx];
    }
    sdata[tid] = sum;
    __syncthreads();
    for (int s = 128; s > 0; s >>= 1) {
        if (tid < s) sdata[tid] += sdata[tid + s];
        __syncthreads();
    }
    if (tid == 0) bsum[blockIdx.x] = sdata[0];
}

// phase B: serial exclusive scan of block sums (<=64 entries), write total
__global__ void k_scan_b(int* __restrict__ bsum, int nb, int* __restrict__ rowptr, int n) {
    if (threadIdx.x == 0 && blockIdx.x == 0) {
        int acc = 0;
        for (int i = 0; i < nb; i++) { int v = bsum[i]; bsum[i] = acc; acc += v; }
        rowptr[n] = acc;
    }
}

// phase C: per-block exclusive scan -> rowptr, cursor copy, dinv
__global__ void k_scan_c(const int* __restrict__ deg, const int* __restrict__ boff,
                         int* __restrict__ rowptr, int* __restrict__ cursor,
                         float* __restrict__ dinv, int n) {
    __shared__ int tmp[256];
    int base = blockIdx.x * 2048;
    int tid = threadIdx.x;
    int local[8];
    int tsum = 0;
    #pragma unroll
    for (int j = 0; j < 8; j++) {
        int idx = base + tid * 8 + j;
        int v = (idx < n) ? deg[idx] : 0;
        local[j] = tsum;
        tsum += v;
    }
    tmp[tid] = tsum;
    __syncthreads();
    for (int off = 1; off < 256; off <<= 1) {
        int v = (tid >= off) ? tmp[tid - off] : 0;
        __syncthreads();
        tmp[tid] += v;
        __syncthreads();
    }
    int excl = tmp[tid] - tsum;
    int baseOff = boff[blockIdx.x] + excl;
    #pragma unroll
    for (int j = 0; j < 8; j++) {
        int idx = base + tid * 8 + j;
        if (idx < n) {
            int rp = baseOff + local[j];
            rowptr[idx] = rp;
            cursor[idx] = rp;
            dinv[idx] = rsqrtf((float)deg[idx] + 1.0f);
        }
    }
}

__global__ void k_fill(const int* __restrict__ src, const int* __restrict__ dst,
                       int* __restrict__ cursor, int* __restrict__ csr, int E) {
    int i = blockIdx.x * blockDim.x + threadIdx.x;
    if (i < E) {
        int p = atomicAdd(&cursor[dst[i]], 1);
        csr[p] = src[i];
    }
}

// ---------------- GEMM (vector-ALU f32; W staged in LDS) ----------------
// Y[row][col] = op( X[row][:] @ W[:, col] )
template<int K, int H, bool SCALE, bool BIAS>
__global__ void k_gemm(const float* __restrict__ X, const float* __restrict__ W,
                       const float* __restrict__ bias, const float* __restrict__ dinv,
                       float* __restrict__ Y, int n) {
    __shared__ float Wl[K * H];
    for (int i = threadIdx.x; i < K * H; i += 256) Wl[i] = W[i];
    __syncthreads();
    const int RPB = 16;                 // rows per block
    const int RIF = 256 / H;            // rows in flight
    int col = threadIdx.x % H;
    int rof = threadIdx.x / H;
    int rowBase = blockIdx.x * RPB;
    for (int r = rof; r < RPB; r += RIF) {
        int row = rowBase + r;
        if (row >= n) continue;
        const float* xr = X + (size_t)row * K;
        float acc = 0.f;
        #pragma unroll
        for (int k = 0; k < K; k += 4) {
            float4 xv = *reinterpret_cast<const float4*>(xr + k);
            acc = fmaf(xv.x, Wl[(k + 0) * H + col], acc);
            acc = fmaf(xv.y, Wl[(k + 1) * H + col], acc);
            acc = fmaf(xv.z, Wl[(k + 2) * H + col], acc);
            acc = fmaf(xv.w, Wl[(k + 3) * H + col], acc);
        }
        if (SCALE) acc *= dinv[row];
        if (BIAS)  acc += bias[col];
        Y[(size_t)row * H + col] = acc;
    }
}

// ---------------- Aggregation: one wave per node, lane = feature (H=64) ----
__global__ void k_agg(const int* __restrict__ rowptr, const int* __restrict__ csr,
                      const float* __restrict__ y, const float* __restrict__ dinv,
                      const float* __restrict__ bias, float* __restrict__ out, int n) {
    int wave = (int)((blockIdx.x * (size_t)blockDim.x + threadIdx.x) >> 6);
    int lane = threadIdx.x & 63;
    if (wave >= n) return;
    int node = wave;
    float acc = y[(size_t)node * 64 + lane];  // self-loop term (y = dinv*xw)
    int s = rowptr[node];
    int e = rowptr[node + 1];
    for (int base = s; base < e; base += 64) {
        int cnt = e - base; if (cnt > 64) cnt = 64;
        int idx = (base + lane < e) ? csr[base + lane] : 0;
        for (int j = 0; j < cnt; j++) {
            int srcn = __shfl(idx, j);
            acc += y[(size_t)srcn * 64 + lane];
        }
    }
    float v = dinv[node] * acc + bias[lane];
    out[(size_t)node * 64 + lane] = fmaxf(v, 0.f);
}

// ---------------- launch ----------------

extern "C" void kernel_launch(void* const* d_in, const int* in_sizes, int n_in,
                              void* d_out, int out_size, void* d_ws, size_t ws_size,
                              hipStream_t stream) {
    const float* x  = (const float*)d_in[0];
    const int*   ei = (const int*)d_in[1];
    const float* W1 = (const float*)d_in[2];
    const float* b1 = (const float*)d_in[3];
    const float* W2 = (const float*)d_in[4];
    const float* b2 = (const float*)d_in[5];
    const float* Wl = (const float*)d_in[6];
    const float* bl = (const float*)d_in[7];
    float* out = (float*)d_out;

    const int n = in_sizes[0] / 128;     // 100000
    const int E = in_sizes[1] / 2;       // 3200000
    const int* src = ei;
    const int* dst = ei + E;

    // workspace carve-up (256B aligned)
    char* p = (char*)d_ws;
    auto alloc = [&](size_t bytes) { char* r = p; p += (bytes + 255) & ~(size_t)255; return r; };
    float* dinv   = (float*)alloc((size_t)n * 4);
    int*   deg    = (int*)  alloc((size_t)n * 4);
    int*   rowptr = (int*)  alloc((size_t)(n + 1) * 4);
    int*   cursor = (int*)  alloc((size_t)n * 4);
    int*   bsum   = (int*)  alloc(256 * 4);
    int*   csr    = (int*)  alloc((size_t)E * 4);
    float* bufY   = (float*)alloc((size_t)n * 64 * 4);
    float* bufA   = (float*)alloc((size_t)n * 64 * 4);
    float* bufB   = (float*)alloc((size_t)n * 64 * 4);
    (void)ws_size;

    const int NB = (n + 2047) / 2048;    // scan blocks (49)

    hipMemsetAsync(deg, 0, (size_t)n * 4, stream);
    k_count<<<(E + 255) / 256, 256, 0, stream>>>(dst, deg, E);
    k_scan_a<<<NB, 256, 0, stream>>>(deg, bsum, n);
    k_scan_b<<<1, 64, 0, stream>>>(bsum, NB, rowptr, n);
    k_scan_c<<<NB, 256, 0, stream>>>(deg, bsum, rowptr, cursor, dinv, n);
    k_fill<<<(E + 255) / 256, 256, 0, stream>>>(src, dst, cursor, csr, E);

    // layer 1: y = dinv ⊙ (x @ W1); h1 = relu(dinv*agg + b1)
    k_gemm<128, 64, true, false><<<(n + 15) / 16, 256, 0, stream>>>(x, W1, nullptr, dinv, bufY, n);
    k_agg<<<(n + 3) / 4, 256, 0, stream>>>(rowptr, csr, bufY, dinv, b1, bufA, n);

    // layer 2
    k_gemm<64, 64, true, false><<<(n + 15) / 16, 256, 0, stream>>>(bufA, W2, nullptr, dinv, bufB, n);
    k_agg<<<(n + 3) / 4, 256, 0, stream>>>(rowptr, csr, bufB, dinv, b2, bufA, n);

    // head: out = h2 @ Wl + bl
    k_gemm<64, 32, false, true><<<(n + 15) / 16, 256, 0, stream>>>(bufA, Wl, bl, nullptr, out, n);
}

// Round 2
// 689.323 us; speedup vs baseline: 1.3839x; 1.3839x over previous
//
#include <hip/hip_runtime.h>

// ---------------- CSR build ----------------

__global__ void k_count(const int* __restrict__ dst, int* __restrict__ deg, int E) {
    int i = blockIdx.x * blockDim.x + threadIdx.x;
    if (i < E) atomicAdd(&deg[dst[i]], 1);
}

// phase A: per-block sums of 2048-element chunks
__global__ void k_scan_a(const int* __restrict__ deg, int* __restrict__ bsum, int n) {
    __shared__ int sdata[256];
    int base = blockIdx.x * 2048;
    int tid = threadIdx.x;
    int sum = 0;
    #pragma unroll
    for (int j = 0; j < 8; j++) {
        int idx = base + tid * 8 + j;
        if (idx < n) sum += deg[idx];
    }
    sdata[tid] = sum;
    __syncthreads();
    for (int s = 128; s > 0; s >>= 1) {
        if (tid < s) sdata[tid] += sdata[tid + s];
        __syncthreads();
    }
    if (tid == 0) bsum[blockIdx.x] = sdata[0];
}

// phase B: serial exclusive scan of block sums (<=64 entries), write total
__global__ void k_scan_b(int* __restrict__ bsum, int nb, int* __restrict__ rowptr, int n) {
    if (threadIdx.x == 0 && blockIdx.x == 0) {
        int acc = 0;
        for (int i = 0; i < nb; i++) { int v = bsum[i]; bsum[i] = acc; acc += v; }
        rowptr[n] = acc;
    }
}

// phase C: per-block exclusive scan -> rowptr, cursor copy, dinv
__global__ void k_scan_c(const int* __restrict__ deg, const int* __restrict__ boff,
                         int* __restrict__ rowptr, int* __restrict__ cursor,
                         float* __restrict__ dinv, int n) {
    __shared__ int tmp[256];
    int base = blockIdx.x * 2048;
    int tid = threadIdx.x;
    int local[8];
    int tsum = 0;
    #pragma unroll
    for (int j = 0; j < 8; j++) {
        int idx = base + tid * 8 + j;
        int v = (idx < n) ? deg[idx] : 0;
        local[j] = tsum;
        tsum += v;
    }
    tmp[tid] = tsum;
    __syncthreads();
    for (int off = 1; off < 256; off <<= 1) {
        int v = (tid >= off) ? tmp[tid - off] : 0;
        __syncthreads();
        tmp[tid] += v;
        __syncthreads();
    }
    int excl = tmp[tid] - tsum;
    int baseOff = boff[blockIdx.x] + excl;
    #pragma unroll
    for (int j = 0; j < 8; j++) {
        int idx = base + tid * 8 + j;
        if (idx < n) {
            int rp = baseOff + local[j];
            rowptr[idx] = rp;
            cursor[idx] = rp;
            dinv[idx] = rsqrtf((float)deg[idx] + 1.0f);
        }
    }
}

// XCD-binned fill: bin = blockIdx % 8 maps to XCD round-robin; all writes to a
// CSR line happen within one XCD's L2 -> full-line eviction instead of 16
// partial-line evictions from 8 different L2s.
__global__ void k_fill_xcd(const int* __restrict__ src, const int* __restrict__ dst,
                           int* __restrict__ cursor, int* __restrict__ csr,
                           int E, int binsz) {
    int grp  = blockIdx.x & 7;
    int slot = blockIdx.x >> 3;
    int lo = grp * binsz, hi = lo + binsz;
    int stride = (gridDim.x >> 3) * blockDim.x;
    for (int e = slot * blockDim.x + threadIdx.x; e < E; e += stride) {
        int d = dst[e];
        if (d >= lo && d < hi) {
            int p = atomicAdd(&cursor[d], 1);
            csr[p] = src[e];
        }
    }
}

// ---------------- GEMM (vector-ALU f32; W staged in LDS) ----------------
template<int K, int H, bool SCALE, bool BIAS>
__global__ void k_gemm(const float* __restrict__ X, const float* __restrict__ W,
                       const float* __restrict__ bias, const float* __restrict__ dinv,
                       float* __restrict__ Y, int n) {
    __shared__ float Wl[K * H];
    for (int i = threadIdx.x; i < K * H; i += 256) Wl[i] = W[i];
    __syncthreads();
    const int RPB = 16;                 // rows per block
    const int RIF = 256 / H;            // rows in flight
    int col = threadIdx.x % H;
    int rof = threadIdx.x / H;
    int rowBase = blockIdx.x * RPB;
    for (int r = rof; r < RPB; r += RIF) {
        int row = rowBase + r;
        if (row >= n) continue;
        const float* xr = X + (size_t)row * K;
        float acc = 0.f;
        #pragma unroll
        for (int k = 0; k < K; k += 4) {
            float4 xv = *reinterpret_cast<const float4*>(xr + k);
            acc = fmaf(xv.x, Wl[(k + 0) * H + col], acc);
            acc = fmaf(xv.y, Wl[(k + 1) * H + col], acc);
            acc = fmaf(xv.z, Wl[(k + 2) * H + col], acc);
            acc = fmaf(xv.w, Wl[(k + 3) * H + col], acc);
        }
        if (SCALE) acc *= dinv[row];
        if (BIAS)  acc += bias[col];
        Y[(size_t)row * H + col] = acc;
    }
}

// ---------------- Aggregation: one wave per node, lane = feature (H=64) ----
__global__ void k_agg(const int* __restrict__ rowptr, const int* __restrict__ csr,
                      const float* __restrict__ y, const float* __restrict__ dinv,
                      const float* __restrict__ bias, float* __restrict__ out, int n) {
    int wave = (int)((blockIdx.x * (size_t)blockDim.x + threadIdx.x) >> 6);
    int lane = threadIdx.x & 63;
    if (wave >= n) return;
    int node = wave;
    float a0 = y[(size_t)node * 64 + lane];  // self-loop term (y = dinv*xw)
    float a1 = 0.f, a2 = 0.f, a3 = 0.f;
    int s = rowptr[node];
    int e = rowptr[node + 1];
    for (int base = s; base < e; base += 64) {
        int rem = e - base; int cnt = rem > 64 ? 64 : rem;
        int idx = (base + lane < e) ? csr[base + lane] : 0;
        int j = 0;
        for (; j + 4 <= cnt; j += 4) {
            int s0 = __shfl(idx, j);
            int s1 = __shfl(idx, j + 1);
            int s2 = __shfl(idx, j + 2);
            int s3 = __shfl(idx, j + 3);
            float v0 = y[(size_t)s0 * 64 + lane];
            float v1 = y[(size_t)s1 * 64 + lane];
            float v2 = y[(size_t)s2 * 64 + lane];
            float v3 = y[(size_t)s3 * 64 + lane];
            a0 += v0; a1 += v1; a2 += v2; a3 += v3;
        }
        for (; j < cnt; j++) {
            int s0 = __shfl(idx, j);
            a0 += y[(size_t)s0 * 64 + lane];
        }
    }
    float v = dinv[node] * ((a0 + a1) + (a2 + a3)) + bias[lane];
    out[(size_t)node * 64 + lane] = fmaxf(v, 0.f);
}

// ---------------- launch ----------------

extern "C" void kernel_launch(void* const* d_in, const int* in_sizes, int n_in,
                              void* d_out, int out_size, void* d_ws, size_t ws_size,
                              hipStream_t stream) {
    const float* x  = (const float*)d_in[0];
    const int*   ei = (const int*)d_in[1];
    const float* W1 = (const float*)d_in[2];
    const float* b1 = (const float*)d_in[3];
    const float* W2 = (const float*)d_in[4];
    const float* b2 = (const float*)d_in[5];
    const float* Wl = (const float*)d_in[6];
    const float* bl = (const float*)d_in[7];
    float* out = (float*)d_out;

    const int n = in_sizes[0] / 128;     // 100000
    const int E = in_sizes[1] / 2;       // 3200000
    const int* src = ei;
    const int* dst = ei + E;

    // workspace carve-up (256B aligned)
    char* p = (char*)d_ws;
    auto alloc = [&](size_t bytes) { char* r = p; p += (bytes + 255) & ~(size_t)255; return r; };
    float* dinv   = (float*)alloc((size_t)n * 4);
    int*   deg    = (int*)  alloc((size_t)n * 4);
    int*   rowptr = (int*)  alloc((size_t)(n + 1) * 4);
    int*   cursor = (int*)  alloc((size_t)n * 4);
    int*   bsum   = (int*)  alloc(256 * 4);
    int*   csr    = (int*)  alloc((size_t)E * 4);
    float* bufY   = (float*)alloc((size_t)n * 64 * 4);
    float* bufA   = (float*)alloc((size_t)n * 64 * 4);
    float* bufB   = (float*)alloc((size_t)n * 64 * 4);
    (void)ws_size;

    const int NB = (n + 2047) / 2048;    // scan blocks (49)

    hipMemsetAsync(deg, 0, (size_t)n * 4, stream);
    k_count<<<(E + 255) / 256, 256, 0, stream>>>(dst, deg, E);
    k_scan_a<<<NB, 256, 0, stream>>>(deg, bsum, n);
    k_scan_b<<<1, 64, 0, stream>>>(bsum, NB, rowptr, n);
    k_scan_c<<<NB, 256, 0, stream>>>(deg, bsum, rowptr, cursor, dinv, n);
    // 2048 blocks: 256 per bin-group, group = blockIdx % 8 (XCD round-robin)
    k_fill_xcd<<<2048, 256, 0, stream>>>(src, dst, cursor, csr, E, (n + 7) / 8);

    // layer 1: y = dinv ⊙ (x @ W1); h1 = relu(dinv*agg + b1)
    k_gemm<128, 64, true, false><<<(n + 15) / 16, 256, 0, stream>>>(x, W1, nullptr, dinv, bufY, n);
    k_agg<<<(n + 3) / 4, 256, 0, stream>>>(rowptr, csr, bufY, dinv, b1, bufA, n);

    // layer 2
    k_gemm<64, 64, true, false><<<(n + 15) / 16, 256, 0, stream>>>(bufA, W2, nullptr, dinv, bufB, n);
    k_agg<<<(n + 3) / 4, 256, 0, stream>>>(rowptr, csr, bufB, dinv, b2, bufA, n);

    // head: out = h2 @ Wl + bl
    k_gemm<64, 32, false, true><<<(n + 15) / 16, 256, 0, stream>>>(bufA, Wl, bl, nullptr, out, n);
}